// Round 4
// baseline (363.726 us; speedup 1.0000x reference)
//
#include <hip/hip_runtime.h>
#include <hip/hip_bf16.h>

#define B_   64
#define L_   2048
#define D_   512
#define SEG_ 32         // segments over L for the two gather passes
#define RPS_ 64         // rows per segment (L_/SEG_)

// ---------- helpers ----------

// lane0-valid sum
__device__ __forceinline__ float wave_sum(float x) {
#pragma unroll
  for (int off = 32; off > 0; off >>= 1) x += __shfl_down(x, off, 64);
  return x;
}

__device__ __forceinline__ float dot8(float4 e0, float4 e1, float4 a0, float4 a1) {
  return e0.x * a0.x + e0.y * a0.y + e0.z * a0.z + e0.w * a0.w +
         e1.x * a1.x + e1.y * a1.y + e1.z * a1.z + e1.w * a1.w;
}

// ---------- K1: partial sums of embedding rows (for h) ----------
// grid (SEG_, B_) = 2048 blocks, block 256 (4 waves). Wave covers a full
// 512-col fp32 row (lane loads float4 at col lane*4 and 256+lane*4),
// 16 rows per wave, batched 4 at a time for MLP.
__global__ __launch_bounds__(256, 8) void k_hpart(const int* __restrict__ tok,
                                                  const float* __restrict__ emb,
                                                  float* __restrict__ A) {
  const int seg = blockIdx.x, b = blockIdx.y;
  const int t = threadIdx.x, w = t >> 6, lane = t & 63;
  __shared__ int lt[RPS_];
  __shared__ float buf[4 * D_];
  if (t < RPS_) lt[t] = tok[b * L_ + seg * RPS_ + t] + 1;
  __syncthreads();
  float acc[8];
#pragma unroll
  for (int j = 0; j < 8; ++j) acc[j] = 0.f;
#pragma unroll
  for (int it = 0; it < RPS_ / 16; ++it) {   // 4 batches x 4 rows
    float4 e[4][2];
#pragma unroll
    for (int j = 0; j < 4; ++j) {
      const int row = lt[it * 16 + j * 4 + w];
      const float4* rp = (const float4*)(emb + (size_t)row * D_);
      e[j][0] = rp[lane];
      e[j][1] = rp[lane + 64];
    }
#pragma unroll
    for (int j = 0; j < 4; ++j) {
      acc[0] += e[j][0].x; acc[1] += e[j][0].y; acc[2] += e[j][0].z; acc[3] += e[j][0].w;
      acc[4] += e[j][1].x; acc[5] += e[j][1].y; acc[6] += e[j][1].z; acc[7] += e[j][1].w;
    }
  }
#pragma unroll
  for (int j = 0; j < 4; ++j) {
    buf[w * D_ + lane * 4 + j]       = acc[j];
    buf[w * D_ + 256 + lane * 4 + j] = acc[4 + j];
  }
  __syncthreads();
  const int c = 2 * t;
  float s0 = buf[c] + buf[D_ + c] + buf[2 * D_ + c] + buf[3 * D_ + c];
  float s1 = buf[c + 1] + buf[D_ + c + 1] + buf[2 * D_ + c + 1] + buf[3 * D_ + c + 1];
  float* o = A + ((size_t)seg * B_ + b) * D_;
  o[c] = s0; o[c + 1] = s1;
}

// ---------- K2: v[b] = W_b @ h[b] / L ----------
// grid (8, B_) = 512 blocks. Block (g,b): reduce h[b] from A into LDS, then
// each wave computes 16 output rows d in [g*64 + w*16, +16).
__global__ __launch_bounds__(256) void k_v(const float* __restrict__ A,
                                           const float* __restrict__ Wb,
                                           float* __restrict__ v) {
  const int g = blockIdx.x, b = blockIdx.y;
  const int t = threadIdx.x, w = t >> 6, lane = t & 63;
  __shared__ float sh[D_];
  float s0 = 0.f, s1 = 0.f;
#pragma unroll 8
  for (int s = 0; s < SEG_; ++s) {
    const float* hp = A + ((size_t)s * B_ + b) * D_;
    s0 += hp[2 * t]; s1 += hp[2 * t + 1];
  }
  sh[2 * t] = s0; sh[2 * t + 1] = s1;
  __syncthreads();
  const float4* shv = (const float4*)sh;
  const float4 a0 = shv[lane];        // cols lane*4 .. +3
  const float4 a1 = shv[lane + 64];   // cols 256+lane*4 .. +3
  const int d0 = g * 64 + w * 16;
#pragma unroll 4
  for (int i = 0; i < 16; ++i) {
    const int d = d0 + i;
    const float4* rp = (const float4*)(Wb + (size_t)d * D_);
    float acc = dot8(rp[lane], rp[lane + 64], a0, a1);
    acc = wave_sum(acc);
    if (lane == 0) v[(size_t)b * D_ + d] = acc * (1.f / (float)L_);
  }
}

// ---------- K3: fused scores+softmax+weighted-sum (flash-style) ----------
// grid (SEG_, B_) = 2048 blocks. Per wave: 16 rows in 4 batches of 4;
// one online-softmax rescale per batch; 4 shfl-reduce chains interleaved.
// Block-combine across 4 waves; write per-segment unnormalized acc (at
// block max M) + (M, s_tot) to ws.
__global__ __launch_bounds__(256, 6) void k_flash(const int* __restrict__ tok,
                                                  const float* __restrict__ emb,
                                                  const float* __restrict__ v,
                                                  float* __restrict__ A,
                                                  float* __restrict__ ms) {
  const int seg = blockIdx.x, b = blockIdx.y;
  const int t = threadIdx.x, w = t >> 6, lane = t & 63;
  __shared__ int lt[RPS_];
  __shared__ float sv[D_];
  __shared__ float red[4][2];
  __shared__ float buf[4 * D_];
  if (t < RPS_) lt[t] = tok[b * L_ + seg * RPS_ + t] + 1;
  sv[t] = v[(size_t)b * D_ + t];
  sv[t + 256] = v[(size_t)b * D_ + t + 256];
  __syncthreads();
  const float4* svv = (const float4*)sv;
  const float4 a0 = svv[lane], a1 = svv[lane + 64];
  float m = -1e30f, s = 0.f;
  float acc[8];
#pragma unroll
  for (int j = 0; j < 8; ++j) acc[j] = 0.f;
#pragma unroll
  for (int it = 0; it < RPS_ / 16; ++it) {   // 4 batches x 4 rows
    float4 e[4][2];
#pragma unroll
    for (int j = 0; j < 4; ++j) {
      const int row = lt[it * 16 + j * 4 + w];
      const float4* rp = (const float4*)(emb + (size_t)row * D_);
      e[j][0] = rp[lane];
      e[j][1] = rp[lane + 64];
    }
    float d0 = dot8(e[0][0], e[0][1], a0, a1);
    float d1 = dot8(e[1][0], e[1][1], a0, a1);
    float d2 = dot8(e[2][0], e[2][1], a0, a1);
    float d3 = dot8(e[3][0], e[3][1], a0, a1);
#pragma unroll
    for (int mask = 1; mask < 64; mask <<= 1) {   // 4 chains interleaved
      d0 += __shfl_xor(d0, mask, 64);
      d1 += __shfl_xor(d1, mask, 64);
      d2 += __shfl_xor(d2, mask, 64);
      d3 += __shfl_xor(d3, mask, 64);
    }
    const float mn = fmaxf(fmaxf(fmaxf(d0, d1), fmaxf(d2, d3)), m);
    const float al = __expf(m - mn);
    const float p0 = __expf(d0 - mn), p1 = __expf(d1 - mn);
    const float p2 = __expf(d2 - mn), p3 = __expf(d3 - mn);
    s = s * al + (p0 + p1 + p2 + p3);
    acc[0] = acc[0] * al + p0 * e[0][0].x + p1 * e[1][0].x + p2 * e[2][0].x + p3 * e[3][0].x;
    acc[1] = acc[1] * al + p0 * e[0][0].y + p1 * e[1][0].y + p2 * e[2][0].y + p3 * e[3][0].y;
    acc[2] = acc[2] * al + p0 * e[0][0].z + p1 * e[1][0].z + p2 * e[2][0].z + p3 * e[3][0].z;
    acc[3] = acc[3] * al + p0 * e[0][0].w + p1 * e[1][0].w + p2 * e[2][0].w + p3 * e[3][0].w;
    acc[4] = acc[4] * al + p0 * e[0][1].x + p1 * e[1][1].x + p2 * e[2][1].x + p3 * e[3][1].x;
    acc[5] = acc[5] * al + p0 * e[0][1].y + p1 * e[1][1].y + p2 * e[2][1].y + p3 * e[3][1].y;
    acc[6] = acc[6] * al + p0 * e[0][1].z + p1 * e[1][1].z + p2 * e[2][1].z + p3 * e[3][1].z;
    acc[7] = acc[7] * al + p0 * e[0][1].w + p1 * e[1][1].w + p2 * e[2][1].w + p3 * e[3][1].w;
    m = mn;
  }
  if (lane == 0) { red[w][0] = m; red[w][1] = s; }
  __syncthreads();
  const float M = fmaxf(fmaxf(red[0][0], red[1][0]), fmaxf(red[2][0], red[3][0]));
  const float scw = __expf(m - M);     // m is wave-uniform
#pragma unroll
  for (int j = 0; j < 4; ++j) {
    buf[w * D_ + lane * 4 + j]       = acc[j] * scw;
    buf[w * D_ + 256 + lane * 4 + j] = acc[4 + j] * scw;
  }
  __syncthreads();
  const int c = 2 * t;
  float o0 = buf[c] + buf[D_ + c] + buf[2 * D_ + c] + buf[3 * D_ + c];
  float o1 = buf[c + 1] + buf[D_ + c + 1] + buf[2 * D_ + c + 1] + buf[3 * D_ + c + 1];
  float* oa = A + ((size_t)seg * B_ + b) * D_;   // A reuse: k_v already consumed it
  oa[c] = o0; oa[c + 1] = o1;
  if (t == 0) {
    float st = red[0][1] * __expf(red[0][0] - M) + red[1][1] * __expf(red[1][0] - M)
             + red[2][1] * __expf(red[2][0] - M) + red[3][1] * __expf(red[3][0] - M);
    ms[((size_t)seg * B_ + b) * 2]     = M;
    ms[((size_t)seg * B_ + b) * 2 + 1] = st;
  }
}

// ---------- K4: merge segment partials -> out ----------
__global__ __launch_bounds__(256) void k_merge(const float* __restrict__ A,
                                               const float* __restrict__ ms,
                                               float* __restrict__ out) {
  const int b = blockIdx.x;
  const int t = threadIdx.x;
  __shared__ float wseg[SEG_];
  if (t == 0) {
    float M = -1e30f;
#pragma unroll
    for (int s = 0; s < SEG_; ++s) M = fmaxf(M, ms[((size_t)s * B_ + b) * 2]);
    float den = 0.f;
#pragma unroll
    for (int s = 0; s < SEG_; ++s)
      den += ms[((size_t)s * B_ + b) * 2 + 1] * __expf(ms[((size_t)s * B_ + b) * 2] - M);
    const float inv = 1.f / den;
#pragma unroll
    for (int s = 0; s < SEG_; ++s)
      wseg[s] = __expf(ms[((size_t)s * B_ + b) * 2] - M) * inv;
  }
  __syncthreads();
  const int c = 2 * t;
  float o0 = 0.f, o1 = 0.f;
#pragma unroll
  for (int s = 0; s < SEG_; ++s) {
    const float* oa = A + ((size_t)s * B_ + b) * D_;
    const float ww = wseg[s];
    o0 += ww * oa[c]; o1 += ww * oa[c + 1];
  }
  out[(size_t)b * D_ + c] = o0;
  out[(size_t)b * D_ + c + 1] = o1;
}

// ---------- launch ----------
extern "C" void kernel_launch(void* const* d_in, const int* in_sizes, int n_in,
                              void* d_out, int out_size, void* d_ws, size_t ws_size,
                              hipStream_t stream) {
  const int* tok = (const int*)d_in[0];
  const float* emb = (const float*)d_in[1];
  const float* Wb  = (const float*)d_in[2];
  float* out = (float*)d_out;
  float* ws = (float*)d_ws;

  float* A  = ws;               // SEG_*B_*D_ = 1048576 floats (h partials, then flash partials)
  float* v  = ws + 1048576;     // B_*D_ = 32768 floats
  float* ms = ws + 1081344;     // SEG_*B_*2 = 4096 floats   (total ~4.3 MB)

  k_hpart<<<dim3(SEG_, B_), 256, 0, stream>>>(tok, emb, A);
  k_v    <<<dim3(8, B_),    256, 0, stream>>>(A, Wb, v);
  k_flash<<<dim3(SEG_, B_), 256, 0, stream>>>(tok, emb, v, A, ms);
  k_merge<<<B_,             256, 0, stream>>>(A, ms, out);
}

// Round 5
// 278.554 us; speedup vs baseline: 1.3058x; 1.3058x over previous
//
#include <hip/hip_runtime.h>
#include <hip/hip_bf16.h>

#define B_   64
#define L_   2048
#define D_   512
#define SEG_ 32         // segments over L for the two gather passes
#define RPS_ 64         // rows per segment (L_/SEG_)

// ---------- helpers ----------

// lane0-valid sum
__device__ __forceinline__ float wave_sum(float x) {
#pragma unroll
  for (int off = 32; off > 0; off >>= 1) x += __shfl_down(x, off, 64);
  return x;
}

__device__ __forceinline__ float dot8(float4 e0, float4 e1, float4 a0, float4 a1) {
  return e0.x * a0.x + e0.y * a0.y + e0.z * a0.z + e0.w * a0.w +
         e1.x * a1.x + e1.y * a1.y + e1.z * a1.z + e1.w * a1.w;
}

// ---------- K1: partial sums of embedding rows (for h) ----------
// grid (SEG_, B_) = 2048 blocks, block 256 (4 waves). Wave covers a full
// 512-col fp32 row (lane loads float4 at col lane*4 and 256+lane*4),
// 16 rows per wave, batched 4 at a time for MLP.
// launch_bounds(256,4): VGPR cap 128 — batch-4 needs ~60 live, NO SPILL.
// (round 4's (256,8) cap=64 forced scratch spill: 300 MB writes, 2x slowdown)
__global__ __launch_bounds__(256, 4) void k_hpart(const int* __restrict__ tok,
                                                  const float* __restrict__ emb,
                                                  float* __restrict__ A) {
  const int seg = blockIdx.x, b = blockIdx.y;
  const int t = threadIdx.x, w = t >> 6, lane = t & 63;
  __shared__ int lt[RPS_];
  __shared__ float buf[4 * D_];
  if (t < RPS_) lt[t] = tok[b * L_ + seg * RPS_ + t] + 1;
  __syncthreads();
  float acc[8];
#pragma unroll
  for (int j = 0; j < 8; ++j) acc[j] = 0.f;
#pragma unroll
  for (int it = 0; it < RPS_ / 16; ++it) {   // 4 batches x 4 rows
    float4 e[4][2];
#pragma unroll
    for (int j = 0; j < 4; ++j) {
      const int row = lt[it * 16 + j * 4 + w];
      const float4* rp = (const float4*)(emb + (size_t)row * D_);
      e[j][0] = rp[lane];
      e[j][1] = rp[lane + 64];
    }
#pragma unroll
    for (int j = 0; j < 4; ++j) {
      acc[0] += e[j][0].x; acc[1] += e[j][0].y; acc[2] += e[j][0].z; acc[3] += e[j][0].w;
      acc[4] += e[j][1].x; acc[5] += e[j][1].y; acc[6] += e[j][1].z; acc[7] += e[j][1].w;
    }
  }
#pragma unroll
  for (int j = 0; j < 4; ++j) {
    buf[w * D_ + lane * 4 + j]       = acc[j];
    buf[w * D_ + 256 + lane * 4 + j] = acc[4 + j];
  }
  __syncthreads();
  const int c = 2 * t;
  float s0 = buf[c] + buf[D_ + c] + buf[2 * D_ + c] + buf[3 * D_ + c];
  float s1 = buf[c + 1] + buf[D_ + c + 1] + buf[2 * D_ + c + 1] + buf[3 * D_ + c + 1];
  float* o = A + ((size_t)seg * B_ + b) * D_;
  o[c] = s0; o[c + 1] = s1;
}

// ---------- K2: v[b] = W_b @ h[b] / L ----------
// grid (8, B_) = 512 blocks. Block (g,b): reduce h[b] from A into LDS, then
// each wave computes 16 output rows d in [g*64 + w*16, +16).
__global__ __launch_bounds__(256) void k_v(const float* __restrict__ A,
                                           const float* __restrict__ Wb,
                                           float* __restrict__ v) {
  const int g = blockIdx.x, b = blockIdx.y;
  const int t = threadIdx.x, w = t >> 6, lane = t & 63;
  __shared__ float sh[D_];
  float s0 = 0.f, s1 = 0.f;
#pragma unroll 8
  for (int s = 0; s < SEG_; ++s) {
    const float* hp = A + ((size_t)s * B_ + b) * D_;
    s0 += hp[2 * t]; s1 += hp[2 * t + 1];
  }
  sh[2 * t] = s0; sh[2 * t + 1] = s1;
  __syncthreads();
  const float4* shv = (const float4*)sh;
  const float4 a0 = shv[lane];        // cols lane*4 .. +3
  const float4 a1 = shv[lane + 64];   // cols 256+lane*4 .. +3
  const int d0 = g * 64 + w * 16;
#pragma unroll 4
  for (int i = 0; i < 16; ++i) {
    const int d = d0 + i;
    const float4* rp = (const float4*)(Wb + (size_t)d * D_);
    float acc = dot8(rp[lane], rp[lane + 64], a0, a1);
    acc = wave_sum(acc);
    if (lane == 0) v[(size_t)b * D_ + d] = acc * (1.f / (float)L_);
  }
}

// ---------- K3: fused scores+softmax+weighted-sum (flash-style) ----------
// grid (SEG_, B_) = 2048 blocks. Per wave: 16 rows in 4 batches of 4;
// one online-softmax rescale per batch; 4 shfl-reduce chains interleaved.
// launch_bounds(256,4): VGPR cap 128 — no spill (see k_hpart note).
__global__ __launch_bounds__(256, 4) void k_flash(const int* __restrict__ tok,
                                                  const float* __restrict__ emb,
                                                  const float* __restrict__ v,
                                                  float* __restrict__ A,
                                                  float* __restrict__ ms) {
  const int seg = blockIdx.x, b = blockIdx.y;
  const int t = threadIdx.x, w = t >> 6, lane = t & 63;
  __shared__ int lt[RPS_];
  __shared__ float sv[D_];
  __shared__ float red[4][2];
  __shared__ float buf[4 * D_];
  if (t < RPS_) lt[t] = tok[b * L_ + seg * RPS_ + t] + 1;
  sv[t] = v[(size_t)b * D_ + t];
  sv[t + 256] = v[(size_t)b * D_ + t + 256];
  __syncthreads();
  const float4* svv = (const float4*)sv;
  const float4 a0 = svv[lane], a1 = svv[lane + 64];
  float m = -1e30f, s = 0.f;
  float acc[8];
#pragma unroll
  for (int j = 0; j < 8; ++j) acc[j] = 0.f;
#pragma unroll
  for (int it = 0; it < RPS_ / 16; ++it) {   // 4 batches x 4 rows
    float4 e[4][2];
#pragma unroll
    for (int j = 0; j < 4; ++j) {
      const int row = lt[it * 16 + j * 4 + w];
      const float4* rp = (const float4*)(emb + (size_t)row * D_);
      e[j][0] = rp[lane];
      e[j][1] = rp[lane + 64];
    }
    float d0 = dot8(e[0][0], e[0][1], a0, a1);
    float d1 = dot8(e[1][0], e[1][1], a0, a1);
    float d2 = dot8(e[2][0], e[2][1], a0, a1);
    float d3 = dot8(e[3][0], e[3][1], a0, a1);
#pragma unroll
    for (int mask = 1; mask < 64; mask <<= 1) {   // 4 chains interleaved
      d0 += __shfl_xor(d0, mask, 64);
      d1 += __shfl_xor(d1, mask, 64);
      d2 += __shfl_xor(d2, mask, 64);
      d3 += __shfl_xor(d3, mask, 64);
    }
    const float mn = fmaxf(fmaxf(fmaxf(d0, d1), fmaxf(d2, d3)), m);
    const float al = __expf(m - mn);
    const float p0 = __expf(d0 - mn), p1 = __expf(d1 - mn);
    const float p2 = __expf(d2 - mn), p3 = __expf(d3 - mn);
    s = s * al + (p0 + p1 + p2 + p3);
    acc[0] = acc[0] * al + p0 * e[0][0].x + p1 * e[1][0].x + p2 * e[2][0].x + p3 * e[3][0].x;
    acc[1] = acc[1] * al + p0 * e[0][0].y + p1 * e[1][0].y + p2 * e[2][0].y + p3 * e[3][0].y;
    acc[2] = acc[2] * al + p0 * e[0][0].z + p1 * e[1][0].z + p2 * e[2][0].z + p3 * e[3][0].z;
    acc[3] = acc[3] * al + p0 * e[0][0].w + p1 * e[1][0].w + p2 * e[2][0].w + p3 * e[3][0].w;
    acc[4] = acc[4] * al + p0 * e[0][1].x + p1 * e[1][1].x + p2 * e[2][1].x + p3 * e[3][1].x;
    acc[5] = acc[5] * al + p0 * e[0][1].y + p1 * e[1][1].y + p2 * e[2][1].y + p3 * e[3][1].y;
    acc[6] = acc[6] * al + p0 * e[0][1].z + p1 * e[1][1].z + p2 * e[2][1].z + p3 * e[3][1].z;
    acc[7] = acc[7] * al + p0 * e[0][1].w + p1 * e[1][1].w + p2 * e[2][1].w + p3 * e[3][1].w;
    m = mn;
  }
  if (lane == 0) { red[w][0] = m; red[w][1] = s; }
  __syncthreads();
  const float M = fmaxf(fmaxf(red[0][0], red[1][0]), fmaxf(red[2][0], red[3][0]));
  const float scw = __expf(m - M);     // m is wave-uniform
#pragma unroll
  for (int j = 0; j < 4; ++j) {
    buf[w * D_ + lane * 4 + j]       = acc[j] * scw;
    buf[w * D_ + 256 + lane * 4 + j] = acc[4 + j] * scw;
  }
  __syncthreads();
  const int c = 2 * t;
  float o0 = buf[c] + buf[D_ + c] + buf[2 * D_ + c] + buf[3 * D_ + c];
  float o1 = buf[c + 1] + buf[D_ + c + 1] + buf[2 * D_ + c + 1] + buf[3 * D_ + c + 1];
  float* oa = A + ((size_t)seg * B_ + b) * D_;   // A reuse: k_v already consumed it
  oa[c] = o0; oa[c + 1] = o1;
  if (t == 0) {
    float st = red[0][1] * __expf(red[0][0] - M) + red[1][1] * __expf(red[1][0] - M)
             + red[2][1] * __expf(red[2][0] - M) + red[3][1] * __expf(red[3][0] - M);
    ms[((size_t)seg * B_ + b) * 2]     = M;
    ms[((size_t)seg * B_ + b) * 2 + 1] = st;
  }
}

// ---------- K4: merge segment partials -> out ----------
__global__ __launch_bounds__(256) void k_merge(const float* __restrict__ A,
                                               const float* __restrict__ ms,
                                               float* __restrict__ out) {
  const int b = blockIdx.x;
  const int t = threadIdx.x;
  __shared__ float wseg[SEG_];
  if (t == 0) {
    float M = -1e30f;
#pragma unroll
    for (int s = 0; s < SEG_; ++s) M = fmaxf(M, ms[((size_t)s * B_ + b) * 2]);
    float den = 0.f;
#pragma unroll
    for (int s = 0; s < SEG_; ++s)
      den += ms[((size_t)s * B_ + b) * 2 + 1] * __expf(ms[((size_t)s * B_ + b) * 2] - M);
    const float inv = 1.f / den;
#pragma unroll
    for (int s = 0; s < SEG_; ++s)
      wseg[s] = __expf(ms[((size_t)s * B_ + b) * 2] - M) * inv;
  }
  __syncthreads();
  const int c = 2 * t;
  float o0 = 0.f, o1 = 0.f;
#pragma unroll
  for (int s = 0; s < SEG_; ++s) {
    const float* oa = A + ((size_t)s * B_ + b) * D_;
    const float ww = wseg[s];
    o0 += ww * oa[c]; o1 += ww * oa[c + 1];
  }
  out[(size_t)b * D_ + c] = o0;
  out[(size_t)b * D_ + c + 1] = o1;
}

// ---------- launch ----------
extern "C" void kernel_launch(void* const* d_in, const int* in_sizes, int n_in,
                              void* d_out, int out_size, void* d_ws, size_t ws_size,
                              hipStream_t stream) {
  const int* tok = (const int*)d_in[0];
  const float* emb = (const float*)d_in[1];
  const float* Wb  = (const float*)d_in[2];
  float* out = (float*)d_out;
  float* ws = (float*)d_ws;

  float* A  = ws;               // SEG_*B_*D_ = 1048576 floats (h partials, then flash partials)
  float* v  = ws + 1048576;     // B_*D_ = 32768 floats
  float* ms = ws + 1081344;     // SEG_*B_*2 = 4096 floats   (total ~4.3 MB)

  k_hpart<<<dim3(SEG_, B_), 256, 0, stream>>>(tok, emb, A);
  k_v    <<<dim3(8, B_),    256, 0, stream>>>(A, Wb, v);
  k_flash<<<dim3(SEG_, B_), 256, 0, stream>>>(tok, emb, v, A, ms);
  k_merge<<<B_,             256, 0, stream>>>(A, ms, out);
}